// Round 9
// baseline (425.638 us; speedup 1.0000x reference)
//
#include <hip/hip_runtime.h>
#include <hip/hip_bf16.h>

// ---------------------------------------------------------------------------
// GraphSAGE 3-layer + global mean pool, fp32 in/out.
//   layer: agg = mean_{e:dst=n} relu(h[src_e]);  h' = agg@Wl^T + bl + h@Wr^T
// R1: sorted-batch pool -> segment reduction.                 810->537us
// R2: parallel scan + wave64 agg + relu-elision.              537->449us
// R3-R5: bf16 MFMA hi/lo split GEMM (3 MFMAs, fp32-class).    449->387us
// R6: layer-2 linearity swap (gather 40-dim not 128-dim).     387->378us
// R7: edge-parallel agg REGRESSED (boundary logic). REVERTED.
// R8: agg-GEMM fusion REGRESSED (gather lost wave parallelism: 6.2k vs
//     12.5k waves, 35% occ). REVERTED. gemm80 packing KEPT.
// R9: (a) revert to R6 agg/mfma structure; (b) keep gemm80+packed agg40;
//     (c) fuse 6-dispatch CSR/weights prep into ONE persistent kernel with
//     device-scope spin barriers (256 blocks co-resident; ~5-8us/dispatch
//     overhead measured from R5->R6 deltas).
// ---------------------------------------------------------------------------

#define NODES 50000
#define K_DIM 128
#define N_GRAPHS 128
#define PREP_BLOCKS 256

typedef __attribute__((ext_vector_type(8))) short short8;
typedef __attribute__((ext_vector_type(4))) short short4v;
typedef __attribute__((ext_vector_type(4))) float f32x4;

__device__ inline short f2bf(float f) {
    unsigned u = __builtin_bit_cast(unsigned, f);
    u += 0x7FFFu + ((u >> 16) & 1u);          // RNE
    return (short)(u >> 16);
}
__device__ inline float bf2f(short h) {
    unsigned u = ((unsigned)(unsigned short)h) << 16;
    return __builtin_bit_cast(float, u);
}
// pack: bits[15:0]=hi bf16, bits[31:16]=lo bf16
__device__ inline unsigned hilo_pack(float f) {
    short h = f2bf(f);
    short l = f2bf(f - bf2f(h));
    return ((unsigned)(unsigned short)h) | (((unsigned)(unsigned short)l) << 16);
}

// ---------------- fused prep: CSR build + weight conversion + pool bounds ---
// One persistent kernel, PREP_BLOCKS blocks x 256 threads (co-resident),
// device-scope spin barrier. barcnt zeroed via memset before launch.
__device__ inline void grid_bar(int* cnt, int phase) {
    __syncthreads();
    if (threadIdx.x == 0) {
        __threadfence();
        atomicAdd(cnt, 1);
        int target = PREP_BLOCKS * phase;
        while (atomicAdd(cnt, 0) < target) __builtin_amdgcn_s_sleep(8);
        __threadfence();
    }
    __syncthreads();
}

__global__ __launch_bounds__(256) void prep_kernel(
        const int* __restrict__ src, const int* __restrict__ dst, int E,
        const int* __restrict__ batch,
        const float* __restrict__ w0, const float* __restrict__ w1,
        const float* __restrict__ w2, const float* __restrict__ w3,
        const float* __restrict__ w4, const float* __restrict__ w5,
        short* __restrict__ whi, short* __restrict__ wlo,
        int* __restrict__ deg, int* __restrict__ bsum,
        int* __restrict__ rowptr, int* __restrict__ fillp,
        int* __restrict__ csr, int* __restrict__ gstart,
        int* __restrict__ barcnt, int N) {
    const int tid = threadIdx.x;
    const int gthread = blockIdx.x * 256 + tid;
    const int GSTRIDE = PREP_BLOCKS * 256;
    const int NB = (N + 255) / 256;          // 196

    __shared__ int ws4[4];
    __shared__ int sboff[PREP_BLOCKS];

    // ---- phase 0: zero deg; wconv; bounds ----
    for (int i = gthread; i < N; i += GSTRIDE) deg[i] = 0;
    {
        const int TOT = 4 * 16384 + 96 * 128;   // 77824
        for (int idx = gthread; idx < TOT; idx += GSTRIDE) {
            float v;
            if (idx < 65536) {
                int m = idx >> 14, e = idx & 16383;
                const float* W = (m == 0) ? w0 : (m == 1) ? w1 : (m == 2) ? w2 : w3;
                v = W[e];
            } else {
                int i2 = idx - 65536;
                int row = i2 >> 7, col = i2 & 127;
                if (row < 40)      v = w4[row * 128 + col];
                else if (row < 80) v = w5[(row - 40) * 128 + col];
                else               v = 0.f;
            }
            unsigned p = hilo_pack(v);
            whi[idx] = (short)(p & 0xFFFFu);
            wlo[idx] = (short)(p >> 16);
        }
    }
    if (blockIdx.x == PREP_BLOCKS - 1 && tid <= N_GRAPHS) {
        int g = tid;
        int lo = 0, hi = N;
        while (lo < hi) {
            int mid = (lo + hi) >> 1;
            if (batch[mid] < g) lo = mid + 1; else hi = mid;
        }
        gstart[g] = lo;
    }
    grid_bar(barcnt, 1);

    // ---- phase 1: degree count ----
    for (int e = gthread; e < E; e += GSTRIDE) atomicAdd(&deg[dst[e]], 1);
    grid_bar(barcnt, 2);

    // ---- phase 2: per-chunk sums (block b -> bsum[b]) ----
    if (blockIdx.x < NB) {
        int i = blockIdx.x * 256 + tid;
        int v = (i < N) ? deg[i] : 0;
        #pragma unroll
        for (int off = 32; off > 0; off >>= 1) v += __shfl_down(v, off, 64);
        int lane = tid & 63, wv = tid >> 6;
        if (lane == 0) ws4[wv] = v;
        __syncthreads();
        if (tid == 0) bsum[blockIdx.x] = ws4[0] + ws4[1] + ws4[2] + ws4[3];
    }
    grid_bar(barcnt, 3);

    // ---- phase 3: every block scans bsum locally, writes its rowptr chunk --
    {
        int lane = tid & 63, wv = tid >> 6;
        // exclusive scan of bsum[0..NB) into sboff
        {
            int v = (tid < NB) ? bsum[tid] : 0;
            int incl = v;
            #pragma unroll
            for (int off = 1; off < 64; off <<= 1) {
                int t = __shfl_up(incl, off, 64);
                if (lane >= off) incl += t;
            }
            if (lane == 63) ws4[wv] = incl;
            __syncthreads();
            int add = 0;
            for (int k = 0; k < wv; ++k) add += ws4[k];
            sboff[tid] = incl + add - v;
            __syncthreads();
        }
        if (blockIdx.x < NB) {
            int i = blockIdx.x * 256 + tid;
            int v = (i < N) ? deg[i] : 0;
            int incl = v;
            #pragma unroll
            for (int off = 1; off < 64; off <<= 1) {
                int t = __shfl_up(incl, off, 64);
                if (lane >= off) incl += t;
            }
            __shared__ int ws4b[4];
            if (lane == 63) ws4b[wv] = incl;
            __syncthreads();
            int add = 0;
            for (int k = 0; k < wv; ++k) add += ws4b[k];
            int excl = sboff[blockIdx.x] + incl + add - v;
            if (i < N) { rowptr[i] = excl; fillp[i] = excl; }
            if (i == N) rowptr[N] = excl;
        }
    }
    grid_bar(barcnt, 4);

    // ---- phase 4: CSR fill ----
    for (int e = gthread; e < E; e += GSTRIDE) {
        int p = atomicAdd(&fillp[dst[e]], 1);
        csr[p] = src[e];
    }
}

// ---------------- aggregation (128-dim): one wave64 per node ----------------
template <bool RELU>
__global__ void agg_kernel(const float* __restrict__ h, const int* __restrict__ rowptr,
                           const int* __restrict__ csr_src, float* __restrict__ agg, int N) {
    int w = (blockIdx.x * blockDim.x + threadIdx.x) >> 6;
    if (w >= N) return;
    int lane = threadIdx.x & 63;
    int half = lane >> 5, l32 = lane & 31;
    int s = rowptr[w], e = rowptr[w + 1];
    float4 acc = make_float4(0.f, 0.f, 0.f, 0.f);
    int i = s + half;
    for (; i + 2 < e; i += 4) {
        int s0 = csr_src[i], s1 = csr_src[i + 2];
        float4 v0 = reinterpret_cast<const float4*>(h + (size_t)s0 * K_DIM)[l32];
        float4 v1 = reinterpret_cast<const float4*>(h + (size_t)s1 * K_DIM)[l32];
        if (RELU) {
            acc.x += fmaxf(v0.x, 0.f) + fmaxf(v1.x, 0.f);
            acc.y += fmaxf(v0.y, 0.f) + fmaxf(v1.y, 0.f);
            acc.z += fmaxf(v0.z, 0.f) + fmaxf(v1.z, 0.f);
            acc.w += fmaxf(v0.w, 0.f) + fmaxf(v1.w, 0.f);
        } else {
            acc.x += v0.x + v1.x; acc.y += v0.y + v1.y;
            acc.z += v0.z + v1.z; acc.w += v0.w + v1.w;
        }
    }
    for (; i < e; i += 2) {
        int s0 = csr_src[i];
        float4 v0 = reinterpret_cast<const float4*>(h + (size_t)s0 * K_DIM)[l32];
        if (RELU) {
            acc.x += fmaxf(v0.x, 0.f); acc.y += fmaxf(v0.y, 0.f);
            acc.z += fmaxf(v0.z, 0.f); acc.w += fmaxf(v0.w, 0.f);
        } else {
            acc.x += v0.x; acc.y += v0.y; acc.z += v0.z; acc.w += v0.w;
        }
    }
    acc.x += __shfl_xor(acc.x, 32, 64);
    acc.y += __shfl_xor(acc.y, 32, 64);
    acc.z += __shfl_xor(acc.z, 32, 64);
    acc.w += __shfl_xor(acc.w, 32, 64);
    if (half == 0) {
        float inv = 1.0f / fmaxf((float)(e - s), 1.0f);
        acc.x *= inv; acc.y *= inv; acc.z *= inv; acc.w *= inv;
        reinterpret_cast<float4*>(agg + (size_t)w * K_DIM)[l32] = acc;
    }
}

// ---------------- MFMA GEMM (L0/L1): out = A@Wl^T + bl + H@Wr^T, relu ------
template <int WAVES_M, int WAVES_N, int WM_TILES, int WN_TILES, int DOUT, bool RELU,
          int PHASES, bool BIAS>
__global__ __launch_bounds__(256) void sage_mfma(
        const float* __restrict__ A, const float* __restrict__ H,
        const short* __restrict__ Bhl, const short* __restrict__ Bll,
        const short* __restrict__ Bhr, const short* __restrict__ Blr,
        const float* __restrict__ bl, float* __restrict__ out, int N) {
    constexpr int BM = WAVES_M * WM_TILES * 16;      // 64
    constexpr int LSTR = 40;                          // shorts per LDS row (20 banks)
    const int tid = threadIdx.x;
    const int lane = tid & 63;
    const int wave = tid >> 6;
    const int wm = wave % WAVES_M;
    const int wn = wave / WAVES_M;
    const int l15 = lane & 15;
    const int quad = lane >> 4;
    const int m0 = blockIdx.x * BM;

    __shared__ __align__(16) short Ahi[BM * LSTR];
    __shared__ __align__(16) short Alo[BM * LSTR];

    f32x4 acc[WM_TILES][WN_TILES];
    #pragma unroll
    for (int i = 0; i < WM_TILES; ++i)
        #pragma unroll
        for (int j = 0; j < WN_TILES; ++j)
            acc[i][j] = (f32x4){0.f, 0.f, 0.f, 0.f};

    #pragma unroll
    for (int ph = 0; ph < PHASES; ++ph) {
        const float* __restrict__ X = ph ? H : A;
        const short* __restrict__ Bh = ph ? Bhr : Bhl;
        const short* __restrict__ Bv = ph ? Blr : Bll;
        for (int k0 = 0; k0 < K_DIM; k0 += 32) {
            __syncthreads();
            #pragma unroll
            for (int r = 0; r < BM * 8 / 256; ++r) {   // 2
                int idx = r * 256 + tid;
                int row = idx >> 3, c4 = idx & 7;
                int m = m0 + row;
                float4 v = make_float4(0.f, 0.f, 0.f, 0.f);
                if (m < N) v = *reinterpret_cast<const float4*>(X + (size_t)m * K_DIM + k0 + c4 * 4);
                unsigned px = hilo_pack(v.x);
                unsigned py = hilo_pack(v.y);
                unsigned pz = hilo_pack(v.z);
                unsigned pw = hilo_pack(v.w);
                short4v h4, l4;
                h4[0] = (short)(px & 0xFFFFu); l4[0] = (short)(px >> 16);
                h4[1] = (short)(py & 0xFFFFu); l4[1] = (short)(py >> 16);
                h4[2] = (short)(pz & 0xFFFFu); l4[2] = (short)(pz >> 16);
                h4[3] = (short)(pw & 0xFFFFu); l4[3] = (short)(pw >> 16);
                *reinterpret_cast<short4v*>(&Ahi[row * LSTR + c4 * 4]) = h4;
                *reinterpret_cast<short4v*>(&Alo[row * LSTR + c4 * 4]) = l4;
            }
            short8 bh[WN_TILES], bo[WN_TILES];
            #pragma unroll
            for (int nt = 0; nt < WN_TILES; ++nt) {
                int n = wn * WN_TILES * 16 + nt * 16 + l15;
                bh[nt] = *reinterpret_cast<const short8*>(Bh + (size_t)n * K_DIM + k0 + quad * 8);
                bo[nt] = *reinterpret_cast<const short8*>(Bv + (size_t)n * K_DIM + k0 + quad * 8);
            }
            __syncthreads();
            #pragma unroll
            for (int mt = 0; mt < WM_TILES; ++mt) {
                int row = wm * WM_TILES * 16 + mt * 16 + l15;
                short8 ah = *reinterpret_cast<const short8*>(&Ahi[row * LSTR + quad * 8]);
                short8 ao = *reinterpret_cast<const short8*>(&Alo[row * LSTR + quad * 8]);
                #pragma unroll
                for (int nt = 0; nt < WN_TILES; ++nt) {
                    acc[mt][nt] = __builtin_amdgcn_mfma_f32_16x16x32_bf16(ah, bh[nt], acc[mt][nt], 0, 0, 0);
                    acc[mt][nt] = __builtin_amdgcn_mfma_f32_16x16x32_bf16(ah, bo[nt], acc[mt][nt], 0, 0, 0);
                    acc[mt][nt] = __builtin_amdgcn_mfma_f32_16x16x32_bf16(ao, bh[nt], acc[mt][nt], 0, 0, 0);
                }
            }
        }
    }

    float bias[WN_TILES];
    #pragma unroll
    for (int nt = 0; nt < WN_TILES; ++nt) {
        int col = wn * WN_TILES * 16 + nt * 16 + l15;
        bias[nt] = (BIAS && col < DOUT) ? bl[col] : 0.f;
    }
    #pragma unroll
    for (int mt = 0; mt < WM_TILES; ++mt) {
        #pragma unroll
        for (int nt = 0; nt < WN_TILES; ++nt) {
            int col = wn * WN_TILES * 16 + nt * 16 + l15;
            #pragma unroll
            for (int reg = 0; reg < 4; ++reg) {
                int row = m0 + wm * WM_TILES * 16 + mt * 16 + quad * 4 + reg;
                if (row < N && col < DOUT) {
                    float v = acc[mt][nt][reg] + bias[nt];
                    if (RELU) v = fmaxf(v, 0.f);
                    out[(size_t)row * DOUT + col] = v;
                }
            }
        }
    }
}

// ---------------- layer-2 GEMM: y80 = h2 @ [Wl2;Wr2]^T (+bl2 on cols 40-79) -
__global__ __launch_bounds__(256) void gemm80(
        const float* __restrict__ X, const short* __restrict__ Bh,
        const short* __restrict__ Bv, const float* __restrict__ b2,
        float* __restrict__ out, int N) {
    constexpr int BM = 64;
    constexpr int LSTR = 40;
    const int tid = threadIdx.x;
    const int lane = tid & 63;
    const int wave = tid >> 6;
    const int wm = wave & 1;
    const int wn = wave >> 1;
    const int l15 = lane & 15;
    const int quad = lane >> 4;
    const int m0 = blockIdx.x * BM;

    __shared__ __align__(16) short Ahi[BM * LSTR];
    __shared__ __align__(16) short Alo[BM * LSTR];

    f32x4 acc[2][3];
    #pragma unroll
    for (int i = 0; i < 2; ++i)
        #pragma unroll
        for (int j = 0; j < 3; ++j) acc[i][j] = (f32x4){0.f, 0.f, 0.f, 0.f};

    for (int k0 = 0; k0 < K_DIM; k0 += 32) {
        __syncthreads();
        #pragma unroll
        for (int r = 0; r < 2; ++r) {
            int idx = r * 256 + tid;
            int row = idx >> 3, c4 = idx & 7;
            int m = m0 + row;
            float4 v = make_float4(0.f, 0.f, 0.f, 0.f);
            if (m < N) v = *reinterpret_cast<const float4*>(X + (size_t)m * K_DIM + k0 + c4 * 4);
            unsigned px = hilo_pack(v.x);
            unsigned py = hilo_pack(v.y);
            unsigned pz = hilo_pack(v.z);
            unsigned pw = hilo_pack(v.w);
            short4v h4, l4;
            h4[0] = (short)(px & 0xFFFFu); l4[0] = (short)(px >> 16);
            h4[1] = (short)(py & 0xFFFFu); l4[1] = (short)(py >> 16);
            h4[2] = (short)(pz & 0xFFFFu); l4[2] = (short)(pz >> 16);
            h4[3] = (short)(pw & 0xFFFFu); l4[3] = (short)(pw >> 16);
            *reinterpret_cast<short4v*>(&Ahi[row * LSTR + c4 * 4]) = h4;
            *reinterpret_cast<short4v*>(&Alo[row * LSTR + c4 * 4]) = l4;
        }
        __syncthreads();
        short8 bh[3], bo[3];
        #pragma unroll
        for (int nt = 0; nt < 3; ++nt) {
            int n = wn * 48 + nt * 16 + l15;   // < 96
            bh[nt] = *reinterpret_cast<const short8*>(Bh + (size_t)n * K_DIM + k0 + quad * 8);
            bo[nt] = *reinterpret_cast<const short8*>(Bv + (size_t)n * K_DIM + k0 + quad * 8);
        }
        #pragma unroll
        for (int mt = 0; mt < 2; ++mt) {
            int row = wm * 32 + mt * 16 + l15;
            short8 ah = *reinterpret_cast<const short8*>(&Ahi[row * LSTR + quad * 8]);
            short8 ao = *reinterpret_cast<const short8*>(&Alo[row * LSTR + quad * 8]);
            #pragma unroll
            for (int nt = 0; nt < 3; ++nt) {
                acc[mt][nt] = __builtin_amdgcn_mfma_f32_16x16x32_bf16(ah, bh[nt], acc[mt][nt], 0, 0, 0);
                acc[mt][nt] = __builtin_amdgcn_mfma_f32_16x16x32_bf16(ah, bo[nt], acc[mt][nt], 0, 0, 0);
                acc[mt][nt] = __builtin_amdgcn_mfma_f32_16x16x32_bf16(ao, bh[nt], acc[mt][nt], 0, 0, 0);
            }
        }
    }

    #pragma unroll
    for (int mt = 0; mt < 2; ++mt) {
        #pragma unroll
        for (int nt = 0; nt < 3; ++nt) {
            int col = wn * 48 + nt * 16 + l15;
            float b = (col >= 40 && col < 80) ? b2[col - 40] : 0.f;
            #pragma unroll
            for (int reg = 0; reg < 4; ++reg) {
                int row = m0 + wm * 32 + mt * 16 + quad * 4 + reg;
                if (row < N && col < 80) {
                    out[(size_t)row * 80 + col] = acc[mt][nt][reg] + b;
                }
            }
        }
    }
}

// ---------------- agg40: out[n] = mean_e yl[src_e] + yr[n] ----------------
// y80 packed: cols 0-39 = yl (h2@Wl2^T), cols 40-79 = yr (h2@Wr2^T + bl2)
__global__ void agg40_kernel(const float* __restrict__ y80,
                             const int* __restrict__ rowptr, const int* __restrict__ csr_src,
                             float* __restrict__ out, int N) {
    int w = (blockIdx.x * blockDim.x + threadIdx.x) >> 6;
    if (w >= N) return;
    int lane = threadIdx.x & 63;
    int s = rowptr[w], e = rowptr[w + 1];
    if (lane >= 40) return;
    float acc = 0.f;
    int i = s;
    for (; i + 3 < e; i += 4) {
        int s0 = csr_src[i], s1 = csr_src[i + 1], s2 = csr_src[i + 2], s3 = csr_src[i + 3];
        float v0 = y80[(size_t)s0 * 80 + lane];
        float v1 = y80[(size_t)s1 * 80 + lane];
        float v2 = y80[(size_t)s2 * 80 + lane];
        float v3 = y80[(size_t)s3 * 80 + lane];
        acc += (v0 + v1) + (v2 + v3);
    }
    for (; i < e; ++i) acc += y80[(size_t)csr_src[i] * 80 + lane];
    float inv = 1.0f / fmaxf((float)(e - s), 1.0f);
    out[(size_t)w * 40 + lane] = acc * inv + y80[(size_t)w * 80 + 40 + lane];
}

// ---------------- pool ----------------
__global__ __launch_bounds__(320) void pool_kernel(const float* __restrict__ h,
                                                   const int* __restrict__ gstart,
                                                   float* __restrict__ g_out) {
    int g = blockIdx.x;
    int tid = threadIdx.x;
    int c = tid % 40, r = tid / 40;
    int s = gstart[g], e = gstart[g + 1];
    float acc = 0.f;
    for (int n = s + r; n < e; n += 8)
        acc += h[(size_t)n * 40 + c];
    __shared__ float sh[8][40];
    sh[r][c] = acc;
    __syncthreads();
    if (r == 0) {
        float sum = 0.f;
        #pragma unroll
        for (int i = 0; i < 8; ++i) sum += sh[i][c];
        g_out[g * 40 + c] = sum / fmaxf((float)(e - s), 1.0f);
    }
}

extern "C" void kernel_launch(void* const* d_in, const int* in_sizes, int n_in,
                              void* d_out, int out_size, void* d_ws, size_t ws_size,
                              hipStream_t stream) {
    const float* x    = (const float*)d_in[0];
    const int*   ei   = (const int*)d_in[1];
    const int*   batch= (const int*)d_in[2];
    const float* Wl0  = (const float*)d_in[3];
    const float* bl0  = (const float*)d_in[4];
    const float* Wr0  = (const float*)d_in[5];
    const float* Wl1  = (const float*)d_in[6];
    const float* bl1  = (const float*)d_in[7];
    const float* Wr1  = (const float*)d_in[8];
    const float* Wl2  = (const float*)d_in[9];
    const float* bl2  = (const float*)d_in[10];
    const float* Wr2  = (const float*)d_in[11];

    const int N = in_sizes[0] / K_DIM;       // 50000
    const int E = in_sizes[1] / 2;           // 600000
    const int* src = ei;
    const int* dst = ei + E;

    float* out = (float*)d_out;              // h3 [N,40] then g [128,40]
    float* gsum = out + (size_t)N * 40;

    char* w = (char*)d_ws;
    auto alloc = [&](size_t bytes) {
        char* p = w;
        w += (bytes + 255) & ~(size_t)255;
        return p;
    };
    float* bufA  = (float*)alloc((size_t)N * K_DIM * 4);  // agg scratch
    float* bufB  = (float*)alloc((size_t)N * K_DIM * 4);  // h1
    float* bufC  = (float*)alloc((size_t)N * K_DIM * 4);  // h2
    float* y80   = (float*)alloc((size_t)N * 80 * 4);     // packed yl|yr
    int*   rowptr= (int*)alloc((size_t)(N + 1) * 4);
    int*   deg   = (int*)alloc((size_t)N * 4);
    int*   fillp = (int*)alloc((size_t)N * 4);
    int*   csr   = (int*)alloc((size_t)E * 4);
    int*   bsum  = (int*)alloc(256 * 4);
    int*   gstart= (int*)alloc((size_t)(N_GRAPHS + 1) * 4);
    short* whi   = (short*)alloc(77824 * 2);
    short* wlo   = (short*)alloc(77824 * 2);
    int*   barcnt= (int*)alloc(256);

    (void)hipMemsetAsync(barcnt, 0, 256, stream);

    // fused prep: zero-deg + wconv + bounds | deg | chunk-sums | scan | fill
    prep_kernel<<<PREP_BLOCKS, 256, 0, stream>>>(
        src, dst, E, batch, Wl0, Wr0, Wl1, Wr1, Wl2, Wr2,
        whi, wlo, deg, bsum, rowptr, fillp, csr, gstart, barcnt, N);

    // weight plane offsets (shorts)
    short* hWl0 = whi;          short* lWl0 = wlo;
    short* hWr0 = whi + 16384;  short* lWr0 = wlo + 16384;
    short* hWl1 = whi + 32768;  short* lWl1 = wlo + 32768;
    short* hWr1 = whi + 49152;  short* lWr1 = wlo + 49152;
    short* hW2  = whi + 65536;  short* lW2  = wlo + 65536;

    const int aggGrid  = (N * 64 + 255) / 256;   // 12500
    const int gemmGrid = (N + 63) / 64;          // 782

    // layer 0
    agg_kernel<true><<<aggGrid, 256, 0, stream>>>(x, rowptr, csr, bufA, N);
    sage_mfma<1, 4, 4, 2, 128, true, 2, true><<<gemmGrid, 256, 0, stream>>>(
        bufA, x, hWl0, lWl0, hWr0, lWr0, bl0, bufB, N);
    // layer 1
    agg_kernel<false><<<aggGrid, 256, 0, stream>>>(bufB, rowptr, csr, bufA, N);
    sage_mfma<1, 4, 4, 2, 128, true, 2, true><<<gemmGrid, 256, 0, stream>>>(
        bufA, bufB, hWl1, lWl1, hWr1, lWr1, bl1, bufC, N);
    // layer 2: y80 = h2 @ [Wl2;Wr2]^T (+bl2 on yr half); then packed agg40
    gemm80<<<gemmGrid, 256, 0, stream>>>(bufC, hW2, lW2, bl2, y80, N);
    agg40_kernel<<<aggGrid, 256, 0, stream>>>(y80, rowptr, csr, out, N);

    // global mean pool
    pool_kernel<<<N_GRAPHS, 320, 0, stream>>>(out, gstart, gsum);
}

// Round 10
// 359.553 us; speedup vs baseline: 1.1838x; 1.1838x over previous
//
#include <hip/hip_runtime.h>
#include <hip/hip_bf16.h>

// ---------------------------------------------------------------------------
// GraphSAGE 3-layer + global mean pool, fp32 in/out.
//   layer: agg = mean_{e:dst=n} relu(h[src_e]);  h' = agg@Wl^T + bl + h@Wr^T
// R1: sorted-batch pool -> segment reduction.                 810->537us
// R2: parallel scan + wave64 agg + relu-elision.              537->449us
// R3-R5: bf16 MFMA hi/lo split GEMM (3 MFMAs, fp32-class).    449->387us
// R6: layer-2 linearity swap (gather 40-dim not 128-dim).     387->378us
// R7: edge-parallel agg REGRESSED. R8: agg-GEMM fusion REGRESSED.
// R9: persistent-prep spin barrier REGRESSED (140us: 256 blocks x 5 phases
//     on one atomic cacheline). ALL REVERTED.
// R10: union of proven-good pieces only: R6 agg/sage_mfma + R8 gemm80/agg40
//     + prep with the 3 independent works (zero-deg, wconv, bounds) merged
//     into one trivially-parallel init_kernel (no cross-block sync).
//     13 dispatches vs R6's 16.
// ---------------------------------------------------------------------------

#define NODES 50000
#define K_DIM 128
#define N_GRAPHS 128

typedef __attribute__((ext_vector_type(8))) short short8;
typedef __attribute__((ext_vector_type(4))) short short4v;
typedef __attribute__((ext_vector_type(4))) float f32x4;

__device__ inline short f2bf(float f) {
    unsigned u = __builtin_bit_cast(unsigned, f);
    u += 0x7FFFu + ((u >> 16) & 1u);          // RNE
    return (short)(u >> 16);
}
__device__ inline float bf2f(short h) {
    unsigned u = ((unsigned)(unsigned short)h) << 16;
    return __builtin_bit_cast(float, u);
}
// pack: bits[15:0]=hi bf16, bits[31:16]=lo bf16
__device__ inline unsigned hilo_pack(float f) {
    short h = f2bf(f);
    short l = f2bf(f - bf2f(h));
    return ((unsigned)(unsigned short)h) | (((unsigned)(unsigned short)l) << 16);
}

// ---------------- init: zero deg + wconv + pool bounds (all independent) ----
// shorts layout: Wl0:0 Wr0:16384 Wl1:32768 Wr1:49152, W2pack(96 rows):65536
__global__ void init_kernel(const float* __restrict__ w0, const float* __restrict__ w1,
                            const float* __restrict__ w2, const float* __restrict__ w3,
                            const float* __restrict__ w4, const float* __restrict__ w5,
                            short* __restrict__ whi, short* __restrict__ wlo,
                            int* __restrict__ deg, const int* __restrict__ batch,
                            int* __restrict__ gstart, int N) {
    int idx = blockIdx.x * 256 + threadIdx.x;
    if (idx < N) deg[idx] = 0;
    const int TOT = 4 * 16384 + 96 * 128;   // 77824
    if (idx < TOT) {
        float v;
        if (idx < 65536) {
            int m = idx >> 14, e = idx & 16383;
            const float* W = (m == 0) ? w0 : (m == 1) ? w1 : (m == 2) ? w2 : w3;
            v = W[e];
        } else {
            int i2 = idx - 65536;
            int row = i2 >> 7, col = i2 & 127;
            if (row < 40)      v = w4[row * 128 + col];
            else if (row < 80) v = w5[(row - 40) * 128 + col];
            else               v = 0.f;
        }
        unsigned p = hilo_pack(v);
        whi[idx] = (short)(p & 0xFFFFu);
        wlo[idx] = (short)(p >> 16);
    }
    if (idx <= N_GRAPHS) {
        int g = idx;
        int lo = 0, hi = N;
        while (lo < hi) {
            int mid = (lo + hi) >> 1;
            if (batch[mid] < g) lo = mid + 1; else hi = mid;
        }
        gstart[g] = lo;
    }
}

// ---------------- CSR build ----------------
__global__ void deg_kernel(const int* __restrict__ dst, int* __restrict__ deg, int E) {
    int e = blockIdx.x * blockDim.x + threadIdx.x;
    if (e < E) atomicAdd(&deg[dst[e]], 1);
}

__global__ void scan_p1(const int* __restrict__ deg, int* __restrict__ bsum, int N) {
    int i = blockIdx.x * 256 + threadIdx.x;
    int v = (i < N) ? deg[i] : 0;
    #pragma unroll
    for (int off = 32; off > 0; off >>= 1) v += __shfl_down(v, off, 64);
    __shared__ int ws[4];
    int lane = threadIdx.x & 63, wv = threadIdx.x >> 6;
    if (lane == 0) ws[wv] = v;
    __syncthreads();
    if (threadIdx.x == 0) bsum[blockIdx.x] = ws[0] + ws[1] + ws[2] + ws[3];
}

__global__ void scan_p2(int* __restrict__ bsum, int NB) {
    int tid = threadIdx.x, lane = tid & 63, wv = tid >> 6;
    int v = (tid < NB) ? bsum[tid] : 0;
    int incl = v;
    #pragma unroll
    for (int off = 1; off < 64; off <<= 1) {
        int t = __shfl_up(incl, off, 64);
        if (lane >= off) incl += t;
    }
    __shared__ int ws[4];
    if (lane == 63) ws[wv] = incl;
    __syncthreads();
    int add = 0;
    for (int i = 0; i < wv; ++i) add += ws[i];
    incl += add;
    if (tid < NB) bsum[tid] = incl - v;
}

__global__ void scan_p3(const int* __restrict__ deg, const int* __restrict__ boff,
                        int* __restrict__ rowptr, int* __restrict__ fillpos, int N) {
    int i = blockIdx.x * 256 + threadIdx.x;
    int tid = threadIdx.x, lane = tid & 63, wv = tid >> 6;
    int v = (i < N) ? deg[i] : 0;
    int incl = v;
    #pragma unroll
    for (int off = 1; off < 64; off <<= 1) {
        int t = __shfl_up(incl, off, 64);
        if (lane >= off) incl += t;
    }
    __shared__ int ws[4];
    if (lane == 63) ws[wv] = incl;
    __syncthreads();
    int add = 0;
    for (int k = 0; k < wv; ++k) add += ws[k];
    int excl = boff[blockIdx.x] + incl + add - v;
    if (i < N) { rowptr[i] = excl; fillpos[i] = excl; }
    if (i == N) rowptr[N] = excl;
}

__global__ void fill_kernel(const int* __restrict__ src, const int* __restrict__ dst,
                            int* __restrict__ fillpos, int* __restrict__ csr_src, int E) {
    int e = blockIdx.x * blockDim.x + threadIdx.x;
    if (e < E) {
        int p = atomicAdd(&fillpos[dst[e]], 1);
        csr_src[p] = src[e];
    }
}

// ---------------- aggregation (128-dim): one wave64 per node ----------------
template <bool RELU>
__global__ void agg_kernel(const float* __restrict__ h, const int* __restrict__ rowptr,
                           const int* __restrict__ csr_src, float* __restrict__ agg, int N) {
    int w = (blockIdx.x * blockDim.x + threadIdx.x) >> 6;
    if (w >= N) return;
    int lane = threadIdx.x & 63;
    int half = lane >> 5, l32 = lane & 31;
    int s = rowptr[w], e = rowptr[w + 1];
    float4 acc = make_float4(0.f, 0.f, 0.f, 0.f);
    int i = s + half;
    for (; i + 6 < e; i += 8) {
        int s0 = csr_src[i], s1 = csr_src[i + 2], s2 = csr_src[i + 4], s3 = csr_src[i + 6];
        float4 v0 = reinterpret_cast<const float4*>(h + (size_t)s0 * K_DIM)[l32];
        float4 v1 = reinterpret_cast<const float4*>(h + (size_t)s1 * K_DIM)[l32];
        float4 v2 = reinterpret_cast<const float4*>(h + (size_t)s2 * K_DIM)[l32];
        float4 v3 = reinterpret_cast<const float4*>(h + (size_t)s3 * K_DIM)[l32];
        if (RELU) {
            acc.x += fmaxf(v0.x, 0.f) + fmaxf(v1.x, 0.f) + fmaxf(v2.x, 0.f) + fmaxf(v3.x, 0.f);
            acc.y += fmaxf(v0.y, 0.f) + fmaxf(v1.y, 0.f) + fmaxf(v2.y, 0.f) + fmaxf(v3.y, 0.f);
            acc.z += fmaxf(v0.z, 0.f) + fmaxf(v1.z, 0.f) + fmaxf(v2.z, 0.f) + fmaxf(v3.z, 0.f);
            acc.w += fmaxf(v0.w, 0.f) + fmaxf(v1.w, 0.f) + fmaxf(v2.w, 0.f) + fmaxf(v3.w, 0.f);
        } else {
            acc.x += v0.x + v1.x + v2.x + v3.x;
            acc.y += v0.y + v1.y + v2.y + v3.y;
            acc.z += v0.z + v1.z + v2.z + v3.z;
            acc.w += v0.w + v1.w + v2.w + v3.w;
        }
    }
    for (; i < e; i += 2) {
        int s0 = csr_src[i];
        float4 v0 = reinterpret_cast<const float4*>(h + (size_t)s0 * K_DIM)[l32];
        if (RELU) {
            acc.x += fmaxf(v0.x, 0.f); acc.y += fmaxf(v0.y, 0.f);
            acc.z += fmaxf(v0.z, 0.f); acc.w += fmaxf(v0.w, 0.f);
        } else {
            acc.x += v0.x; acc.y += v0.y; acc.z += v0.z; acc.w += v0.w;
        }
    }
    acc.x += __shfl_xor(acc.x, 32, 64);
    acc.y += __shfl_xor(acc.y, 32, 64);
    acc.z += __shfl_xor(acc.z, 32, 64);
    acc.w += __shfl_xor(acc.w, 32, 64);
    if (half == 0) {
        float inv = 1.0f / fmaxf((float)(e - s), 1.0f);
        acc.x *= inv; acc.y *= inv; acc.z *= inv; acc.w *= inv;
        reinterpret_cast<float4*>(agg + (size_t)w * K_DIM)[l32] = acc;
    }
}

// ---------------- MFMA GEMM (L0/L1): out = A@Wl^T + bl + H@Wr^T, relu ------
template <int WAVES_M, int WAVES_N, int WM_TILES, int WN_TILES, int DOUT, bool RELU,
          int PHASES, bool BIAS>
__global__ __launch_bounds__(256) void sage_mfma(
        const float* __restrict__ A, const float* __restrict__ H,
        const short* __restrict__ Bhl, const short* __restrict__ Bll,
        const short* __restrict__ Bhr, const short* __restrict__ Blr,
        const float* __restrict__ bl, float* __restrict__ out, int N) {
    constexpr int BM = WAVES_M * WM_TILES * 16;      // 64
    constexpr int LSTR = 40;                          // shorts per LDS row (20 banks)
    const int tid = threadIdx.x;
    const int lane = tid & 63;
    const int wave = tid >> 6;
    const int wm = wave % WAVES_M;
    const int wn = wave / WAVES_M;
    const int l15 = lane & 15;
    const int quad = lane >> 4;
    const int m0 = blockIdx.x * BM;

    __shared__ __align__(16) short Ahi[BM * LSTR];
    __shared__ __align__(16) short Alo[BM * LSTR];

    f32x4 acc[WM_TILES][WN_TILES];
    #pragma unroll
    for (int i = 0; i < WM_TILES; ++i)
        #pragma unroll
        for (int j = 0; j < WN_TILES; ++j)
            acc[i][j] = (f32x4){0.f, 0.f, 0.f, 0.f};

    #pragma unroll
    for (int ph = 0; ph < PHASES; ++ph) {
        const float* __restrict__ X = ph ? H : A;
        const short* __restrict__ Bh = ph ? Bhr : Bhl;
        const short* __restrict__ Bv = ph ? Blr : Bll;
        for (int k0 = 0; k0 < K_DIM; k0 += 32) {
            __syncthreads();
            #pragma unroll
            for (int r = 0; r < BM * 8 / 256; ++r) {   // 2
                int idx = r * 256 + tid;
                int row = idx >> 3, c4 = idx & 7;
                int m = m0 + row;
                float4 v = make_float4(0.f, 0.f, 0.f, 0.f);
                if (m < N) v = *reinterpret_cast<const float4*>(X + (size_t)m * K_DIM + k0 + c4 * 4);
                unsigned px = hilo_pack(v.x);
                unsigned py = hilo_pack(v.y);
                unsigned pz = hilo_pack(v.z);
                unsigned pw = hilo_pack(v.w);
                short4v h4, l4;
                h4[0] = (short)(px & 0xFFFFu); l4[0] = (short)(px >> 16);
                h4[1] = (short)(py & 0xFFFFu); l4[1] = (short)(py >> 16);
                h4[2] = (short)(pz & 0xFFFFu); l4[2] = (short)(pz >> 16);
                h4[3] = (short)(pw & 0xFFFFu); l4[3] = (short)(pw >> 16);
                *reinterpret_cast<short4v*>(&Ahi[row * LSTR + c4 * 4]) = h4;
                *reinterpret_cast<short4v*>(&Alo[row * LSTR + c4 * 4]) = l4;
            }
            short8 bh[WN_TILES], bo[WN_TILES];
            #pragma unroll
            for (int nt = 0; nt < WN_TILES; ++nt) {
                int n = wn * WN_TILES * 16 + nt * 16 + l15;
                bh[nt] = *reinterpret_cast<const short8*>(Bh + (size_t)n * K_DIM + k0 + quad * 8);
                bo[nt] = *reinterpret_cast<const short8*>(Bv + (size_t)n * K_DIM + k0 + quad * 8);
            }
            __syncthreads();
            #pragma unroll
            for (int mt = 0; mt < WM_TILES; ++mt) {
                int row = wm * WM_TILES * 16 + mt * 16 + l15;
                short8 ah = *reinterpret_cast<const short8*>(&Ahi[row * LSTR + quad * 8]);
                short8 ao = *reinterpret_cast<const short8*>(&Alo[row * LSTR + quad * 8]);
                #pragma unroll
                for (int nt = 0; nt < WN_TILES; ++nt) {
                    acc[mt][nt] = __builtin_amdgcn_mfma_f32_16x16x32_bf16(ah, bh[nt], acc[mt][nt], 0, 0, 0);
                    acc[mt][nt] = __builtin_amdgcn_mfma_f32_16x16x32_bf16(ah, bo[nt], acc[mt][nt], 0, 0, 0);
                    acc[mt][nt] = __builtin_amdgcn_mfma_f32_16x16x32_bf16(ao, bh[nt], acc[mt][nt], 0, 0, 0);
                }
            }
        }
    }

    float bias[WN_TILES];
    #pragma unroll
    for (int nt = 0; nt < WN_TILES; ++nt) {
        int col = wn * WN_TILES * 16 + nt * 16 + l15;
        bias[nt] = (BIAS && col < DOUT) ? bl[col] : 0.f;
    }
    #pragma unroll
    for (int mt = 0; mt < WM_TILES; ++mt) {
        #pragma unroll
        for (int nt = 0; nt < WN_TILES; ++nt) {
            int col = wn * WN_TILES * 16 + nt * 16 + l15;
            #pragma unroll
            for (int reg = 0; reg < 4; ++reg) {
                int row = m0 + wm * WM_TILES * 16 + mt * 16 + quad * 4 + reg;
                if (row < N && col < DOUT) {
                    float v = acc[mt][nt][reg] + bias[nt];
                    if (RELU) v = fmaxf(v, 0.f);
                    out[(size_t)row * DOUT + col] = v;
                }
            }
        }
    }
}

// ---------------- layer-2 GEMM: y80 = h2 @ [Wl2;Wr2]^T (+bl2 on cols 40-79) -
__global__ __launch_bounds__(256) void gemm80(
        const float* __restrict__ X, const short* __restrict__ Bh,
        const short* __restrict__ Bv, const float* __restrict__ b2,
        float* __restrict__ out, int N) {
    constexpr int BM = 64;
    constexpr int LSTR = 40;
    const int tid = threadIdx.x;
    const int lane = tid & 63;
    const int wave = tid >> 6;
    const int wm = wave & 1;
    const int wn = wave >> 1;
    const int l15 = lane & 15;
    const int quad = lane >> 4;
    const int m0 = blockIdx.x * BM;

    __shared__ __align__(16) short Ahi[BM * LSTR];
    __shared__ __align__(16) short Alo[BM * LSTR];

    f32x4 acc[2][3];
    #pragma unroll
    for (int i = 0; i < 2; ++i)
        #pragma unroll
        for (int j = 0; j < 3; ++j) acc[i][j] = (f32x4){0.f, 0.f, 0.f, 0.f};

    for (int k0 = 0; k0 < K_DIM; k0 += 32) {
        __syncthreads();
        #pragma unroll
        for (int r = 0; r < 2; ++r) {
            int idx = r * 256 + tid;
            int row = idx >> 3, c4 = idx & 7;
            int m = m0 + row;
            float4 v = make_float4(0.f, 0.f, 0.f, 0.f);
            if (m < N) v = *reinterpret_cast<const float4*>(X + (size_t)m * K_DIM + k0 + c4 * 4);
            unsigned px = hilo_pack(v.x);
            unsigned py = hilo_pack(v.y);
            unsigned pz = hilo_pack(v.z);
            unsigned pw = hilo_pack(v.w);
            short4v h4, l4;
            h4[0] = (short)(px & 0xFFFFu); l4[0] = (short)(px >> 16);
            h4[1] = (short)(py & 0xFFFFu); l4[1] = (short)(py >> 16);
            h4[2] = (short)(pz & 0xFFFFu); l4[2] = (short)(pz >> 16);
            h4[3] = (short)(pw & 0xFFFFu); l4[3] = (short)(pw >> 16);
            *reinterpret_cast<short4v*>(&Ahi[row * LSTR + c4 * 4]) = h4;
            *reinterpret_cast<short4v*>(&Alo[row * LSTR + c4 * 4]) = l4;
        }
        __syncthreads();
        short8 bh[3], bo[3];
        #pragma unroll
        for (int nt = 0; nt < 3; ++nt) {
            int n = wn * 48 + nt * 16 + l15;   // < 96
            bh[nt] = *reinterpret_cast<const short8*>(Bh + (size_t)n * K_DIM + k0 + quad * 8);
            bo[nt] = *reinterpret_cast<const short8*>(Bv + (size_t)n * K_DIM + k0 + quad * 8);
        }
        #pragma unroll
        for (int mt = 0; mt < 2; ++mt) {
            int row = wm * 32 + mt * 16 + l15;
            short8 ah = *reinterpret_cast<const short8*>(&Ahi[row * LSTR + quad * 8]);
            short8 ao = *reinterpret_cast<const short8*>(&Alo[row * LSTR + quad * 8]);
            #pragma unroll
            for (int nt = 0; nt < 3; ++nt) {
                acc[mt][nt] = __builtin_amdgcn_mfma_f32_16x16x32_bf16(ah, bh[nt], acc[mt][nt], 0, 0, 0);
                acc[mt][nt] = __builtin_amdgcn_mfma_f32_16x16x32_bf16(ah, bo[nt], acc[mt][nt], 0, 0, 0);
                acc[mt][nt] = __builtin_amdgcn_mfma_f32_16x16x32_bf16(ao, bh[nt], acc[mt][nt], 0, 0, 0);
            }
        }
    }

    #pragma unroll
    for (int mt = 0; mt < 2; ++mt) {
        #pragma unroll
        for (int nt = 0; nt < 3; ++nt) {
            int col = wn * 48 + nt * 16 + l15;
            float b = (col >= 40 && col < 80) ? b2[col - 40] : 0.f;
            #pragma unroll
            for (int reg = 0; reg < 4; ++reg) {
                int row = m0 + wm * 32 + mt * 16 + quad * 4 + reg;
                if (row < N && col < 80) {
                    out[(size_t)row * 80 + col] = acc[mt][nt][reg] + b;
                }
            }
        }
    }
}

// ---------------- agg40: out[n] = mean_e yl[src_e] + yr[n] ----------------
// y80 packed: cols 0-39 = yl (h2@Wl2^T), cols 40-79 = yr (h2@Wr2^T + bl2)
__global__ void agg40_kernel(const float* __restrict__ y80,
                             const int* __restrict__ rowptr, const int* __restrict__ csr_src,
                             float* __restrict__ out, int N) {
    int w = (blockIdx.x * blockDim.x + threadIdx.x) >> 6;
    if (w >= N) return;
    int lane = threadIdx.x & 63;
    int s = rowptr[w], e = rowptr[w + 1];
    if (lane >= 40) return;
    float acc = 0.f;
    int i = s;
    for (; i + 3 < e; i += 4) {
        int s0 = csr_src[i], s1 = csr_src[i + 1], s2 = csr_src[i + 2], s3 = csr_src[i + 3];
        float v0 = y80[(size_t)s0 * 80 + lane];
        float v1 = y80[(size_t)s1 * 80 + lane];
        float v2 = y80[(size_t)s2 * 80 + lane];
        float v3 = y80[(size_t)s3 * 80 + lane];
        acc += (v0 + v1) + (v2 + v3);
    }
    for (; i < e; ++i) acc += y80[(size_t)csr_src[i] * 80 + lane];
    float inv = 1.0f / fmaxf((float)(e - s), 1.0f);
    out[(size_t)w * 40 + lane] = acc * inv + y80[(size_t)w * 80 + 40 + lane];
}

// ---------------- pool ----------------
__global__ __launch_bounds__(320) void pool_kernel(const float* __restrict__ h,
                                                   const int* __restrict__ gstart,
                                                   float* __restrict__ g_out) {
    int g = blockIdx.x;
    int tid = threadIdx.x;
    int c = tid % 40, r = tid / 40;
    int s = gstart[g], e = gstart[g + 1];
    float acc = 0.f;
    for (int n = s + r; n < e; n += 8)
        acc += h[(size_t)n * 40 + c];
    __shared__ float sh[8][40];
    sh[r][c] = acc;
    __syncthreads();
    if (r == 0) {
        float sum = 0.f;
        #pragma unroll
        for (int i = 0; i < 8; ++i) sum += sh[i][c];
        g_out[g * 40 + c] = sum / fmaxf((float)(e - s), 1.0f);
    }
}

extern "C" void kernel_launch(void* const* d_in, const int* in_sizes, int n_in,
                              void* d_out, int out_size, void* d_ws, size_t ws_size,
                              hipStream_t stream) {
    const float* x    = (const float*)d_in[0];
    const int*   ei   = (const int*)d_in[1];
    const int*   batch= (const int*)d_in[2];
    const float* Wl0  = (const float*)d_in[3];
    const float* bl0  = (const float*)d_in[4];
    const float* Wr0  = (const float*)d_in[5];
    const float* Wl1  = (const float*)d_in[6];
    const float* bl1  = (const float*)d_in[7];
    const float* Wr1  = (const float*)d_in[8];
    const float* Wl2  = (const float*)d_in[9];
    const float* bl2  = (const float*)d_in[10];
    const float* Wr2  = (const float*)d_in[11];

    const int N = in_sizes[0] / K_DIM;       // 50000
    const int E = in_sizes[1] / 2;           // 600000
    const int* src = ei;
    const int* dst = ei + E;

    float* out = (float*)d_out;              // h3 [N,40] then g [128,40]
    float* gsum = out + (size_t)N * 40;

    char* w = (char*)d_ws;
    auto alloc = [&](size_t bytes) {
        char* p = w;
        w += (bytes + 255) & ~(size_t)255;
        return p;
    };
    float* bufA  = (float*)alloc((size_t)N * K_DIM * 4);  // agg scratch
    float* bufB  = (float*)alloc((size_t)N * K_DIM * 4);  // h1
    float* bufC  = (float*)alloc((size_t)N * K_DIM * 4);  // h2
    float* y80   = (float*)alloc((size_t)N * 80 * 4);     // packed yl|yr
    int*   rowptr= (int*)alloc((size_t)(N + 1) * 4);
    int*   deg   = (int*)alloc((size_t)N * 4);
    int*   fillp = (int*)alloc((size_t)N * 4);
    int*   csr   = (int*)alloc((size_t)E * 4);
    int*   bsum  = (int*)alloc(256 * 4);
    int*   gstart= (int*)alloc((size_t)(N_GRAPHS + 1) * 4);
    short* whi   = (short*)alloc(77824 * 2);
    short* wlo   = (short*)alloc(77824 * 2);

    const int NB = (N + 255) / 256;          // 196
    const int initGrid = (77824 + 255) / 256; // covers N, TOT, 129

    // prep: init (zero-deg + wconv + bounds) | deg | p1 | p2 | p3 | fill
    init_kernel<<<initGrid, 256, 0, stream>>>(Wl0, Wr0, Wl1, Wr1, Wl2, Wr2,
                                              whi, wlo, deg, batch, gstart, N);
    deg_kernel<<<(E + 255) / 256, 256, 0, stream>>>(dst, deg, E);
    scan_p1<<<NB, 256, 0, stream>>>(deg, bsum, N);
    scan_p2<<<1, 256, 0, stream>>>(bsum, NB);
    scan_p3<<<NB, 256, 0, stream>>>(deg, bsum, rowptr, fillp, N);
    fill_kernel<<<(E + 255) / 256, 256, 0, stream>>>(src, dst, fillp, csr, E);

    // weight plane offsets (shorts)
    short* hWl0 = whi;          short* lWl0 = wlo;
    short* hWr0 = whi + 16384;  short* lWr0 = wlo + 16384;
    short* hWl1 = whi + 32768;  short* lWl1 = wlo + 32768;
    short* hWr1 = whi + 49152;  short* lWr1 = wlo + 49152;
    short* hW2  = whi + 65536;  short* lW2  = wlo + 65536;

    const int aggGrid  = (N * 64 + 255) / 256;   // 12500
    const int gemmGrid = (N + 63) / 64;          // 782

    // layer 0
    agg_kernel<true><<<aggGrid, 256, 0, stream>>>(x, rowptr, csr, bufA, N);
    sage_mfma<1, 4, 4, 2, 128, true, 2, true><<<gemmGrid, 256, 0, stream>>>(
        bufA, x, hWl0, lWl0, hWr0, lWr0, bl0, bufB, N);
    // layer 1
    agg_kernel<false><<<aggGrid, 256, 0, stream>>>(bufB, rowptr, csr, bufA, N);
    sage_mfma<1, 4, 4, 2, 128, true, 2, true><<<gemmGrid, 256, 0, stream>>>(
        bufA, bufB, hWl1, lWl1, hWr1, lWr1, bl1, bufC, N);
    // layer 2: y80 = h2 @ [Wl2;Wr2]^T (+bl2 on yr half); then packed agg40
    gemm80<<<gemmGrid, 256, 0, stream>>>(bufC, hW2, lW2, bl2, y80, N);
    agg40_kernel<<<aggGrid, 256, 0, stream>>>(y80, rowptr, csr, out, N);

    // global mean pool
    pool_kernel<<<N_GRAPHS, 320, 0, stream>>>(out, gstart, gsum);
}

// Round 11
// 337.035 us; speedup vs baseline: 1.2629x; 1.0668x over previous
//
#include <hip/hip_runtime.h>
#include <hip/hip_bf16.h>

// ---------------------------------------------------------------------------
// GraphSAGE 3-layer + global mean pool, fp32 in/out.
//   layer: agg = mean_{e:dst=n} relu(h[src_e]);  h' = agg@Wl^T + bl + h@Wr^T
// R1: sorted-batch pool -> segment reduction.                 810->537us
// R2: parallel scan + wave64 agg + relu-elision.              537->449us
// R3-R5: bf16 MFMA hi/lo split GEMM (3 MFMAs, fp32-class).    449->387us
// R6: layer-2 linearity swap (gather 40-dim not 128-dim).     387->378us
// R7/R8/R9: edge-parallel agg / agg-GEMM fusion / persistent prep all
//     REGRESSED and were reverted.
// R10: union of proven pieces, 13 dispatches.                 378->360us
// R11: gathers are service-rate-limited by BYTES (R6: ILP-4 neutral) ->
//     gather from bf16 tables: xb=bf16(relu(x)) [init], h1b=bf16(h1)
//     [mfma0 epilogue], ylb=bf16(h2@Wl2^T) [gemm80 epilogue]. Rows 512->256B
//     (L0/L1), 160->80B (agg40). Mean-of-12 + hi/lo GEMM keeps absmax well
//     under threshold (est +0.003). xb/h1b alias dead bufC. Also merged
//     scan_p2+p3 (each block locally scans the 196 block sums). 12 dispatches.
// ---------------------------------------------------------------------------

#define NODES 50000
#define K_DIM 128
#define N_GRAPHS 128

typedef __attribute__((ext_vector_type(8))) short short8;
typedef __attribute__((ext_vector_type(4))) short short4v;
typedef __attribute__((ext_vector_type(4))) float f32x4;

__device__ inline short f2bf(float f) {
    unsigned u = __builtin_bit_cast(unsigned, f);
    u += 0x7FFFu + ((u >> 16) & 1u);          // RNE
    return (short)(u >> 16);
}
__device__ inline float bf2f(short h) {
    unsigned u = ((unsigned)(unsigned short)h) << 16;
    return __builtin_bit_cast(float, u);
}
__device__ inline float blo(unsigned u) { return __builtin_bit_cast(float, u << 16); }
__device__ inline float bhi(unsigned u) { return __builtin_bit_cast(float, u & 0xFFFF0000u); }
// pack: bits[15:0]=hi bf16, bits[31:16]=lo bf16
__device__ inline unsigned hilo_pack(float f) {
    short h = f2bf(f);
    short l = f2bf(f - bf2f(h));
    return ((unsigned)(unsigned short)h) | (((unsigned)(unsigned short)l) << 16);
}

// ---------------- init: zero deg + wconv + bounds + xb=bf16(relu(x)) -------
__global__ void init_kernel(const float* __restrict__ w0, const float* __restrict__ w1,
                            const float* __restrict__ w2, const float* __restrict__ w3,
                            const float* __restrict__ w4, const float* __restrict__ w5,
                            short* __restrict__ whi, short* __restrict__ wlo,
                            int* __restrict__ deg, const int* __restrict__ batch,
                            int* __restrict__ gstart,
                            const float* __restrict__ x, short* __restrict__ xb, int N) {
    int idx = blockIdx.x * 256 + threadIdx.x;
    // xb: bf16(relu(x)), one float4 -> short4 per thread
    if (idx < N * (K_DIM / 4)) {
        float4 v = reinterpret_cast<const float4*>(x)[idx];
        short4v b;
        b[0] = f2bf(fmaxf(v.x, 0.f));
        b[1] = f2bf(fmaxf(v.y, 0.f));
        b[2] = f2bf(fmaxf(v.z, 0.f));
        b[3] = f2bf(fmaxf(v.w, 0.f));
        *reinterpret_cast<short4v*>(&xb[idx * 4]) = b;
    }
    if (idx < N) deg[idx] = 0;
    const int TOT = 4 * 16384 + 96 * 128;   // 77824
    if (idx < TOT) {
        float v;
        if (idx < 65536) {
            int m = idx >> 14, e = idx & 16383;
            const float* W = (m == 0) ? w0 : (m == 1) ? w1 : (m == 2) ? w2 : w3;
            v = W[e];
        } else {
            int i2 = idx - 65536;
            int row = i2 >> 7, col = i2 & 127;
            if (row < 40)      v = w4[row * 128 + col];
            else if (row < 80) v = w5[(row - 40) * 128 + col];
            else               v = 0.f;
        }
        unsigned p = hilo_pack(v);
        whi[idx] = (short)(p & 0xFFFFu);
        wlo[idx] = (short)(p >> 16);
    }
    if (idx <= N_GRAPHS) {
        int g = idx;
        int lo = 0, hi = N;
        while (lo < hi) {
            int mid = (lo + hi) >> 1;
            if (batch[mid] < g) lo = mid + 1; else hi = mid;
        }
        gstart[g] = lo;
    }
}

// ---------------- CSR build ----------------
__global__ void deg_kernel(const int* __restrict__ dst, int* __restrict__ deg, int E) {
    int e = blockIdx.x * blockDim.x + threadIdx.x;
    if (e < E) atomicAdd(&deg[dst[e]], 1);
}

__global__ void scan_p1(const int* __restrict__ deg, int* __restrict__ bsum, int N) {
    int i = blockIdx.x * 256 + threadIdx.x;
    int v = (i < N) ? deg[i] : 0;
    #pragma unroll
    for (int off = 32; off > 0; off >>= 1) v += __shfl_down(v, off, 64);
    __shared__ int ws[4];
    int lane = threadIdx.x & 63, wv = threadIdx.x >> 6;
    if (lane == 0) ws[wv] = v;
    __syncthreads();
    if (threadIdx.x == 0) bsum[blockIdx.x] = ws[0] + ws[1] + ws[2] + ws[3];
}

// merged p2+p3: each block locally exclusive-scans bsum, then writes its chunk
__global__ void scan_p23(const int* __restrict__ deg, const int* __restrict__ bsum,
                         int* __restrict__ rowptr, int* __restrict__ fillpos,
                         int N, int NB) {
    const int tid = threadIdx.x, lane = tid & 63, wv = tid >> 6;
    __shared__ int ws[4];
    __shared__ int sboff[256];
    {   // exclusive scan of bsum[0..NB) into sboff
        int v = (tid < NB) ? bsum[tid] : 0;
        int incl = v;
        #pragma unroll
        for (int off = 1; off < 64; off <<= 1) {
            int t = __shfl_up(incl, off, 64);
            if (lane >= off) incl += t;
        }
        if (lane == 63) ws[wv] = incl;
        __syncthreads();
        int add = 0;
        for (int k = 0; k < wv; ++k) add += ws[k];
        sboff[tid] = incl + add - v;
        __syncthreads();
    }
    const int boff = sboff[blockIdx.x];
    int i = blockIdx.x * 256 + tid;
    int v = (i < N) ? deg[i] : 0;
    int incl = v;
    #pragma unroll
    for (int off = 1; off < 64; off <<= 1) {
        int t = __shfl_up(incl, off, 64);
        if (lane >= off) incl += t;
    }
    __shared__ int ws2[4];
    if (lane == 63) ws2[wv] = incl;
    __syncthreads();
    int add = 0;
    for (int k = 0; k < wv; ++k) add += ws2[k];
    int excl = boff + incl + add - v;
    if (i < N) { rowptr[i] = excl; fillpos[i] = excl; }
    if (i == N) rowptr[N] = excl;
}

__global__ void fill_kernel(const int* __restrict__ src, const int* __restrict__ dst,
                            int* __restrict__ fillpos, int* __restrict__ csr_src, int E) {
    int e = blockIdx.x * blockDim.x + threadIdx.x;
    if (e < E) {
        int p = atomicAdd(&fillpos[dst[e]], 1);
        csr_src[p] = src[e];
    }
}

// ------- aggregation from bf16 table (128-dim): one wave64 per node --------
// row = 256B; half-wave (32 lanes x uint2) covers one row; halves alternate.
__global__ void agg_bf16(const unsigned short* __restrict__ hb,
                         const int* __restrict__ rowptr,
                         const int* __restrict__ csr_src,
                         float* __restrict__ agg, int N) {
    int w = (blockIdx.x * blockDim.x + threadIdx.x) >> 6;
    if (w >= N) return;
    int lane = threadIdx.x & 63;
    int half = lane >> 5, l32 = lane & 31;
    int s = rowptr[w], e = rowptr[w + 1];
    float4 acc = make_float4(0.f, 0.f, 0.f, 0.f);
    int i = s + half;
    for (; i + 6 < e; i += 8) {
        int s0 = csr_src[i], s1 = csr_src[i + 2], s2 = csr_src[i + 4], s3 = csr_src[i + 6];
        uint2 v0 = reinterpret_cast<const uint2*>(hb + (size_t)s0 * K_DIM)[l32];
        uint2 v1 = reinterpret_cast<const uint2*>(hb + (size_t)s1 * K_DIM)[l32];
        uint2 v2 = reinterpret_cast<const uint2*>(hb + (size_t)s2 * K_DIM)[l32];
        uint2 v3 = reinterpret_cast<const uint2*>(hb + (size_t)s3 * K_DIM)[l32];
        acc.x += (blo(v0.x) + blo(v1.x)) + (blo(v2.x) + blo(v3.x));
        acc.y += (bhi(v0.x) + bhi(v1.x)) + (bhi(v2.x) + bhi(v3.x));
        acc.z += (blo(v0.y) + blo(v1.y)) + (blo(v2.y) + blo(v3.y));
        acc.w += (bhi(v0.y) + bhi(v1.y)) + (bhi(v2.y) + bhi(v3.y));
    }
    for (; i < e; i += 2) {
        int s0 = csr_src[i];
        uint2 v0 = reinterpret_cast<const uint2*>(hb + (size_t)s0 * K_DIM)[l32];
        acc.x += blo(v0.x); acc.y += bhi(v0.x);
        acc.z += blo(v0.y); acc.w += bhi(v0.y);
    }
    acc.x += __shfl_xor(acc.x, 32, 64);
    acc.y += __shfl_xor(acc.y, 32, 64);
    acc.z += __shfl_xor(acc.z, 32, 64);
    acc.w += __shfl_xor(acc.w, 32, 64);
    if (half == 0) {
        float inv = 1.0f / fmaxf((float)(e - s), 1.0f);
        acc.x *= inv; acc.y *= inv; acc.z *= inv; acc.w *= inv;
        // lane l32 holds elements l32*4 .. l32*4+3 (lo/hi of 2 dwords)
        reinterpret_cast<float4*>(agg + (size_t)w * K_DIM)[l32] = acc;
    }
}

// ---------------- MFMA GEMM (L0/L1): out = A@Wl^T + bl + H@Wr^T, relu ------
// BF16OUT: additionally write bf16 copy of output (for next layer's gather)
template <int WAVES_M, int WAVES_N, int WM_TILES, int WN_TILES, bool BF16OUT>
__global__ __launch_bounds__(256) void sage_mfma(
        const float* __restrict__ A, const float* __restrict__ H,
        const short* __restrict__ Bhl, const short* __restrict__ Bll,
        const short* __restrict__ Bhr, const short* __restrict__ Blr,
        const float* __restrict__ bl, float* __restrict__ out,
        short* __restrict__ outb, int N) {
    constexpr int BM = WAVES_M * WM_TILES * 16;      // 64
    constexpr int LSTR = 40;                          // shorts per LDS row (20 banks)
    const int tid = threadIdx.x;
    const int lane = tid & 63;
    const int wave = tid >> 6;
    const int wm = wave % WAVES_M;
    const int wn = wave / WAVES_M;
    const int l15 = lane & 15;
    const int quad = lane >> 4;
    const int m0 = blockIdx.x * BM;

    __shared__ __align__(16) short Ahi[BM * LSTR];
    __shared__ __align__(16) short Alo[BM * LSTR];

    f32x4 acc[WM_TILES][WN_TILES];
    #pragma unroll
    for (int i = 0; i < WM_TILES; ++i)
        #pragma unroll
        for (int j = 0; j < WN_TILES; ++j)
            acc[i][j] = (f32x4){0.f, 0.f, 0.f, 0.f};

    #pragma unroll
    for (int ph = 0; ph < 2; ++ph) {
        const float* __restrict__ X = ph ? H : A;
        const short* __restrict__ Bh = ph ? Bhr : Bhl;
        const short* __restrict__ Bv = ph ? Blr : Bll;
        for (int k0 = 0; k0 < K_DIM; k0 += 32) {
            __syncthreads();
            #pragma unroll
            for (int r = 0; r < BM * 8 / 256; ++r) {   // 2
                int idx = r * 256 + tid;
                int row = idx >> 3, c4 = idx & 7;
                int m = m0 + row;
                float4 v = make_float4(0.f, 0.f, 0.f, 0.f);
                if (m < N) v = *reinterpret_cast<const float4*>(X + (size_t)m * K_DIM + k0 + c4 * 4);
                unsigned px = hilo_pack(v.x);
                unsigned py = hilo_pack(v.y);
                unsigned pz = hilo_pack(v.z);
                unsigned pw = hilo_pack(v.w);
                short4v h4, l4;
                h4[0] = (short)(px & 0xFFFFu); l4[0] = (short)(px >> 16);
                h4[1] = (short)(py & 0xFFFFu); l4[1] = (short)(py >> 16);
                h4[2] = (short)(pz & 0xFFFFu); l4[2] = (short)(pz >> 16);
                h4[3] = (short)(pw & 0xFFFFu); l4[3] = (short)(pw >> 16);
                *reinterpret_cast<short4v*>(&Ahi[row * LSTR + c4 * 4]) = h4;
                *reinterpret_cast<short4v*>(&Alo[row * LSTR + c4 * 4]) = l4;
            }
            short8 bh[WN_TILES], bo[WN_TILES];
            #pragma unroll
            for (int nt = 0; nt < WN_TILES; ++nt) {
                int n = wn * WN_TILES * 16 + nt * 16 + l15;
                bh[nt] = *reinterpret_cast<const short8*>(Bh + (size_t)n * K_DIM + k0 + quad * 8);
                bo[nt] = *reinterpret_cast<const short8*>(Bv + (size_t)n * K_DIM + k0 + quad * 8);
            }
            __syncthreads();
            #pragma unroll
            for (int mt = 0; mt < WM_TILES; ++mt) {
                int row = wm * WM_TILES * 16 + mt * 16 + l15;
                short8 ah = *reinterpret_cast<const short8*>(&Ahi[row * LSTR + quad * 8]);
                short8 ao = *reinterpret_cast<const short8*>(&Alo[row * LSTR + quad * 8]);
                #pragma unroll
                for (int nt = 0; nt < WN_TILES; ++nt) {
                    acc[mt][nt] = __builtin_amdgcn_mfma_f32_16x16x32_bf16(ah, bh[nt], acc[mt][nt], 0, 0, 0);
                    acc[mt][nt] = __builtin_amdgcn_mfma_f32_16x16x32_bf16(ah, bo[nt], acc[mt][nt], 0, 0, 0);
                    acc[mt][nt] = __builtin_amdgcn_mfma_f32_16x16x32_bf16(ao, bh[nt], acc[mt][nt], 0, 0, 0);
                }
            }
        }
    }

    #pragma unroll
    for (int mt = 0; mt < WM_TILES; ++mt) {
        #pragma unroll
        for (int nt = 0; nt < WN_TILES; ++nt) {
            int col = wn * WN_TILES * 16 + nt * 16 + l15;
            float b = bl[col];
            #pragma unroll
            for (int reg = 0; reg < 4; ++reg) {
                int row = m0 + wm * WM_TILES * 16 + mt * 16 + quad * 4 + reg;
                if (row < N) {
                    float v = fmaxf(acc[mt][nt][reg] + b, 0.f);
                    out[(size_t)row * K_DIM + col] = v;
                    if (BF16OUT) outb[(size_t)row * K_DIM + col] = f2bf(v);
                }
            }
        }
    }
}

// ------ layer-2 GEMM: ylb = bf16(h2@Wl2^T), yr40 = h2@Wr2^T + bl2 ----------
__global__ __launch_bounds__(256) void gemm80(
        const float* __restrict__ X, const short* __restrict__ Bh,
        const short* __restrict__ Bv, const float* __restrict__ b2,
        short* __restrict__ ylb, float* __restrict__ yr40, int N) {
    constexpr int BM = 64;
    constexpr int LSTR = 40;
    const int tid = threadIdx.x;
    const int lane = tid & 63;
    const int wave = tid >> 6;
    const int wm = wave & 1;
    const int wn = wave >> 1;
    const int l15 = lane & 15;
    const int quad = lane >> 4;
    const int m0 = blockIdx.x * BM;

    __shared__ __align__(16) short Ahi[BM * LSTR];
    __shared__ __align__(16) short Alo[BM * LSTR];

    f32x4 acc[2][3];
    #pragma unroll
    for (int i = 0; i < 2; ++i)
        #pragma unroll
        for (int j = 0; j < 3; ++j) acc[i][j] = (f32x4){0.f, 0.f, 0.f, 0.f};

    for (int k0 = 0; k0 < K_DIM; k0 += 32) {
        __syncthreads();
        #pragma unroll
        for (int r = 0; r < 2; ++r) {
            int idx = r * 256 + tid;
            int row = idx >> 3, c4 = idx & 7;
            int m = m0 + row;
            float4 v = make_float4(0.f, 0.f, 0.f, 0.f);
            if (m < N) v = *reinterpret_cast<const float4*>(X + (size_t)m * K_DIM + k0 + c4 * 4);
            unsigned px = hilo_pack(v.x);
            unsigned py = hilo_pack(v.y);
            unsigned pz = hilo_pack(v.z);
            unsigned pw = hilo_pack(v.w);
            short4v h4, l4;
            h4[0] = (short)(px & 0xFFFFu); l4[0] = (short)(px >> 16);
            h4[1] = (short)(py & 0xFFFFu); l4[1] = (short)(py >> 16);
            h4[2] = (short)(pz & 0xFFFFu); l4[2] = (short)(pz >> 16);
            h4[3] = (short)(pw & 0xFFFFu); l4[3] = (short)(pw >> 16);
            *reinterpret_cast<short4v*>(&Ahi[row * LSTR + c4 * 4]) = h4;
            *reinterpret_cast<short4v*>(&Alo[row * LSTR + c4 * 4]) = l4;
        }
        __syncthreads();
        short8 bh[3], bo[3];
        #pragma unroll
        for (int nt = 0; nt < 3; ++nt) {
            int n = wn * 48 + nt * 16 + l15;   // < 96
            bh[nt] = *reinterpret_cast<const short8*>(Bh + (size_t)n * K_DIM + k0 + quad * 8);
            bo[nt] = *reinterpret_cast<const short8*>(Bv + (size_t)n * K_DIM + k0 + quad * 8);
        }
        #pragma unroll
        for (int mt = 0; mt < 2; ++mt) {
            int row = wm * 32 + mt * 16 + l15;
            short8 ah = *reinterpret_cast<const short8*>(&Ahi[row * LSTR + quad * 8]);
            short8 ao = *reinterpret_cast<const short8*>(&Alo[row * LSTR + quad * 8]);
            #pragma unroll
            for (int nt = 0; nt < 3; ++nt) {
                acc[mt][nt] = __builtin_amdgcn_mfma_f32_16x16x32_bf16(ah, bh[nt], acc[mt][nt], 0, 0, 0);
                acc[mt][nt] = __builtin_amdgcn_mfma_f32_16x16x32_bf16(ah, bo[nt], acc[mt][nt], 0, 0, 0);
                acc[mt][nt] = __builtin_amdgcn_mfma_f32_16x16x32_bf16(ao, bh[nt], acc[mt][nt], 0, 0, 0);
            }
        }
    }

    #pragma unroll
    for (int mt = 0; mt < 2; ++mt) {
        #pragma unroll
        for (int nt = 0; nt < 3; ++nt) {
            int col = wn * 48 + nt * 16 + l15;
            #pragma unroll
            for (int reg = 0; reg < 4; ++reg) {
                int row = m0 + wm * 32 + mt * 16 + quad * 4 + reg;
                if (row < N) {
                    float v = acc[mt][nt][reg];
                    if (col < 40) {
                        ylb[(size_t)row * 40 + col] = f2bf(v);
                    } else if (col < 80) {
                        yr40[(size_t)row * 40 + (col - 40)] = v + b2[col - 40];
                    }
                }
            }
        }
    }
}

// ------- agg40: out[n] = mean_e bf16 ylb[src_e] + yr40[n] ------------------
__global__ void agg40_kernel(const unsigned short* __restrict__ ylb,
                             const float* __restrict__ yr40,
                             const int* __restrict__ rowptr, const int* __restrict__ csr_src,
                             float* __restrict__ out, int N) {
    int w = (blockIdx.x * blockDim.x + threadIdx.x) >> 6;
    if (w >= N) return;
    int lane = threadIdx.x & 63;
    int s = rowptr[w], e = rowptr[w + 1];
    if (lane >= 40) return;
    float acc = 0.f;
    int i = s;
    for (; i + 3 < e; i += 4) {
        int s0 = csr_src[i], s1 = csr_src[i + 1], s2 = csr_src[i + 2], s3 = csr_src[i + 3];
        float v0 = bf2f((short)ylb[(size_t)s0 * 40 + lane]);
        float v1 = bf2f((short)ylb[(size_t)s1 * 40 + lane]);
        float v2 = bf2f((short)ylb[(size_t)s2 * 40 + lane]);
        float v3 = bf2f((short)ylb[(size_t)s3 * 40 + lane]);
        acc += (v0 + v1) + (v2 + v3);
    }
    for (; i < e; ++i) acc += bf2f((short)ylb[(size_t)csr_src[i] * 40 + lane]);
    float inv = 1.0f / fmaxf((float)(e - s), 1.0f);
    out[(size_t)w * 40 + lane] = acc * inv + yr40[(size_t)w * 40 + lane];
}

// ---------------- pool ----------------
__global__ __launch_bounds__(320) void pool_kernel(const float* __restrict__ h,
                                                   const int* __restrict__ gstart,
                                                   float* __restrict__ g_out) {
    int g = blockIdx.x;
    int tid = threadIdx.x;
    int c = tid % 40, r = tid / 40;
    int s = gstart[g], e = gstart[g + 1];
    float acc = 0.f;
    for (int n = s + r; n < e; n += 8)
        acc += h[(size_t)n * 40 + c];
    __shared__ float sh[8][40];
    sh[r][c] = acc;
    __syncthreads();
    if (r == 0) {
        float sum = 0.f;
        #pragma unroll
        for (int i = 0; i < 8; ++i) sum += sh[i][c];
        g_out[g * 40 + c] = sum / fmaxf((float)(e - s), 1.0f);
    }
}

extern "C" void kernel_launch(void* const* d_in, const int* in_sizes, int n_in,
                              void* d_out, int out_size, void* d_ws, size_t ws_size,
                              hipStream_t stream) {
    const float* x    = (const float*)d_in[0];
    const int*   ei   = (const int*)d_in[1];
    const int*   batch= (const int*)d_in[2];
    const float* Wl0  = (const float*)d_in[3];
    const float* bl0  = (const float*)d_in[4];
    const float* Wr0  = (const float*)d_in[5];
    const float* Wl1  = (const float*)d_in[6];
    const float* bl1  = (const float*)d_in[7];
    const float* Wr1  = (const float*)d_in[8];
    const float* Wl2  = (const float*)d_in[9];
    const float* bl2  = (const float*)d_in[10];
    const float* Wr2  = (const float*)d_in[11];

    const int N = in_sizes[0] / K_DIM;       // 50000
    const int E = in_sizes[1] / 2;           // 600000
    const int* src = ei;
    const int* dst = ei + E;

    float* out = (float*)d_out;              // h3 [N,40] then g [128,40]
    float* gsum = out + (size_t)N * 40;

    char* w = (char*)d_ws;
    auto alloc = [&](size_t bytes) {
        char* p = w;
        w += (bytes + 255) & ~(size_t)255;
        return p;
    };
    float* bufA  = (float*)alloc((size_t)N * K_DIM * 4);  // agg scratch (fp32)
    float* bufB  = (float*)alloc((size_t)N * K_DIM * 4);  // h1 fp32
    float* bufC  = (float*)alloc((size_t)N * K_DIM * 4);  // h2 fp32 (aliased early: xb|h1b)
    short* ylb   = (short*)alloc((size_t)N * 40 * 2);     // bf16 h2@Wl2^T
    float* yr40  = (float*)alloc((size_t)N * 40 * 4);     // fp32 h2@Wr2^T + bl2
    int*   rowptr= (int*)alloc((size_t)(N + 1) * 4);
    int*   deg   = (int*)alloc((size_t)N * 4);
    int*   fillp = (int*)alloc((size_t)N * 4);
    int*   csr   = (int*)alloc((size_t)E * 4);
    int*   bsum  = (int*)alloc(256 * 4);
    int*   gstart= (int*)alloc((size_t)(N_GRAPHS + 1) * 4);
    short* whi   = (short*)alloc(77824 * 2);
    short* wlo   = (short*)alloc(77824 * 2);

    // alias bf16 gather tables into bufC (dead until mfma1 writes h2):
    //   xb  = bf16(relu(x)) : N*128 shorts (12.8 MB)  [read by agg0]
    //   h1b = bf16(h1)      : N*128 shorts (12.8 MB)  [written by mfma0, read by agg1]
    short* xb  = (short*)bufC;
    short* h1b = (short*)bufC + (size_t)N * K_DIM;

    const int NB = (N + 255) / 256;              // 196
    const int initGrid = (N * (K_DIM / 4) + 255) / 256;   // 6250, covers all init work

    // prep: init | deg | p1 | p23 | fill        (5 dispatches)
    init_kernel<<<initGrid, 256, 0, stream>>>(Wl0, Wr0, Wl1, Wr1, Wl2, Wr2,
                                              whi, wlo, deg, batch, gstart, x, xb, N);
    deg_kernel<<<(E + 255) / 256, 256, 0, stream>>>(dst, deg, E);
    scan_p1<<<NB, 256, 0, stream>>>(deg, bsum, N);
    scan_p23<<<NB, 256, 0, stream>>>(deg, bsum, rowptr, fillp, N, NB);
    fill_kernel<<<(E + 255) / 256, 256, 0, stream>>>(src, dst, fillp, csr, E);

    // weight plane offsets (shorts)
    short* hWl0 = whi;          short* lWl0 = wlo;
    short* hWr0 = whi + 16384;  short* lWr0 = wlo + 16384;
    short* hWl1 = whi + 32768;  short* lWl1 = wlo + 32768;
    short* hWr1 = whi + 49152;  short* lWr1 = wlo + 49152;
    short* hW2  = whi + 65536;  short* lW2  = wlo + 65536;

    const int aggGrid  = (N * 64 + 255) / 256;   // 12500
    const int gemmGrid = (N + 63) / 64;          // 782

    // layer 0: agg from xb (relu pre-applied), GEMM writes h1 fp32 + h1b bf16
    agg_bf16<<<aggGrid, 256, 0, stream>>>((const unsigned short*)xb, rowptr, csr, bufA, N);
    sage_mfma<1, 4, 4, 2, true><<<gemmGrid, 256, 0, stream>>>(
        bufA, x, hWl0, lWl0, hWr0, lWr0, bl0, bufB, h1b, N);
    // layer 1: agg from h1b (h1 >= 0), GEMM writes h2 fp32 (clobbers xb/h1b - both dead)
    agg_bf16<<<aggGrid, 256, 0, stream>>>((const unsigned short*)h1b, rowptr, csr, bufA, N);
    sage_mfma<1, 4, 4, 2, false><<<gemmGrid, 256, 0, stream>>>(
        bufA, bufB, hWl1, lWl1, hWr1, lWr1, bl1, bufC, nullptr, N);
    // layer 2: gemm80 -> ylb (bf16) + yr40 (fp32); agg40 gathers 80B rows
    gemm80<<<gemmGrid, 256, 0, stream>>>(bufC, hW2, lW2, bl2, ylb, yr40, N);
    agg40_kernel<<<aggGrid, 256, 0, stream>>>((const unsigned short*)ylb, yr40, rowptr, csr, out, N);

    // global mean pool
    pool_kernel<<<N_GRAPHS, 320, 0, stream>>>(out, gstart, gsum);
}